// Round 10
// baseline (313.050 us; speedup 1.0000x reference)
//
#include <hip/hip_runtime.h>
#include <hip/hip_bf16.h>

#define N_NODES 6144
#define IN_F 256
#define N_HEADS 4
#define N_HID 64
#define NWORDS (N_NODES / 32)      // 192 u32 mask words per full row
#define JS 8
#define JLEN (N_NODES / JS)        // 768
#define NW (JLEN / 32)             // 24 mask words per chunk row
#define SMT_STRIDE 100             // words per (wy,m) row: 24*4 + pad, 16B aligned, 2-way banks

typedef __attribute__((ext_vector_type(4))) float floatx4;
typedef _Float16 half2_t __attribute__((ext_vector_type(2)));
typedef _Float16 half8_t __attribute__((ext_vector_type(8)));
typedef __attribute__((ext_vector_type(4))) unsigned uint4_t;
typedef short short2v __attribute__((ext_vector_type(2)));

// ---------------- Kernel 0: pack adj int32 -> bit mask, lane-independent (no ballot).
__global__ __launch_bounds__(256) void pack_adj_kernel(
    const int* __restrict__ adj, unsigned* __restrict__ mask32)
{
    const int waveId = (blockIdx.x * 256 + threadIdx.x) >> 6;   // 0..6143
    const int lane = threadIdx.x & 63;
    #pragma unroll
    for (int c = 0; c < 3; ++c) {
        const size_t W = ((size_t)c * 6144 + waveId) * 64 + lane;
        const int* p = adj + W * 32;
        unsigned mw = 0;
        #pragma unroll
        for (int k = 0; k < 8; ++k) {
            const int4 v = *(const int4*)(p + k * 4);           // adj values are {0,1}
            mw |= (unsigned)v.x << (k * 4 + 0);
            mw |= (unsigned)v.y << (k * 4 + 1);
            mw |= (unsigned)v.z << (k * 4 + 2);
            mw |= (unsigned)v.w << (k * 4 + 3);
        }
        mask32[W] = mw;
    }
}

// ---------------- Kernel 1: ht = h @ W (fp32); epilogue -> htF (f16 MFMA B-fragment layout),
//   srcv (f32), tE1pk/tE2pk = f16x2 pairs of exp(tgt), exp(0.2*tgt).
__global__ __launch_bounds__(256) void ht_gemm_kernel(
    const float* __restrict__ h, const float* __restrict__ W,
    const float* __restrict__ a, short* __restrict__ htF,
    float* __restrict__ srcv, unsigned* __restrict__ tE1pk, unsigned* __restrict__ tE2pk)
{
    __shared__ float As[32][34];
    __shared__ float Bs[32][68];
    __shared__ float redS[32][16];
    __shared__ float redT[32][16];
    __shared__ unsigned short eh1[32], eh2[32];

    const int head = blockIdx.y;
    const int i0 = blockIdx.x * 32;
    const int tid = threadIdx.x;
    const int tx = tid & 15, ty = tid >> 4;

    float acc[2][4] = {};

    for (int k0 = 0; k0 < IN_F; k0 += 32) {
        __syncthreads();
        {
            const int m = tid >> 3, kq = tid & 7;
            const float4 v = *(const float4*)(h + (i0 + m) * IN_F + k0 + kq * 4);
            As[kq*4+0][m] = v.x; As[kq*4+1][m] = v.y;
            As[kq*4+2][m] = v.z; As[kq*4+3][m] = v.w;
        }
        #pragma unroll
        for (int it = 0; it < 2; ++it) {
            int l = it * 256 + tid;
            int k = l >> 4, nq = l & 15;
            *(float4*)&Bs[k][nq*4] = *(const float4*)(W + (k0 + k) * 256 + head * 64 + nq * 4);
        }
        __syncthreads();
        #pragma unroll
        for (int kk = 0; kk < 32; ++kk) {
            const float2 av = *(const float2*)&As[kk][ty*2];
            const float4 bv = *(const float4*)&Bs[kk][tx*4];
            const float aa[2] = {av.x, av.y};
            const float bb[4] = {bv.x, bv.y, bv.z, bv.w};
            #pragma unroll
            for (int r = 0; r < 2; ++r)
                #pragma unroll
                for (int c = 0; c < 4; ++c)
                    acc[r][c] = fmaf(aa[r], bb[c], acc[r][c]);
        }
    }

    #pragma unroll
    for (int r = 0; r < 2; ++r)
        #pragma unroll
        for (int c2 = 0; c2 < 4; ++c2) {
            const int d = tx * 4 + c2;
            const int j = i0 + ty * 2 + r;
            const int jt = j >> 5, q = (j >> 3) & 3, u = j & 7;
            const int c = d >> 4, n = d & 15;
            const size_t F = (((((size_t)head * 192 + jt) * 4 + c) * 16 + n) * 4 + q) * 8 + u;
            const _Float16 hv = (_Float16)acc[r][c2];
            htF[F] = *(const short*)&hv;
        }

    float as_[4], at_[4];
    #pragma unroll
    for (int c = 0; c < 4; ++c) {
        as_[c] = a[head * 128 + tx * 4 + c];
        at_[c] = a[head * 128 + 64 + tx * 4 + c];
    }
    #pragma unroll
    for (int r = 0; r < 2; ++r) {
        float ps = 0.f, pt = 0.f;
        #pragma unroll
        for (int c = 0; c < 4; ++c) {
            ps = fmaf(acc[r][c], as_[c], ps);
            pt = fmaf(acc[r][c], at_[c], pt);
        }
        redS[ty*2+r][tx] = ps;
        redT[ty*2+r][tx] = pt;
    }
    __syncthreads();
    if (tid < 64) {
        const int row = tid & 31;
        const float* src = (tid < 32) ? &redS[row][0] : &redT[row][0];
        float s = 0.f;
        #pragma unroll
        for (int x = 0; x < 16; ++x) s += src[x];
        if (tid < 32) {
            srcv[head * N_NODES + i0 + row] = s;
        } else {
            const _Float16 E1 = (_Float16)__expf(s);
            const _Float16 E2 = (_Float16)__expf(0.2f * s);
            eh1[row] = *(const unsigned short*)&E1;
            eh2[row] = *(const unsigned short*)&E2;
        }
    }
    __syncthreads();
    if (tid < 16) {
        const unsigned v1 = (unsigned)eh1[2*tid] | ((unsigned)eh1[2*tid+1] << 16);
        const unsigned v2 = (unsigned)eh2[2*tid] | ((unsigned)eh2[2*tid+1] << 16);
        tE1pk[head * (N_NODES/2) + i0/2 + tid] = v1;
        tE2pk[head * (N_NODES/2) + i0/2 + tid] = v2;
    }
}

// ---------------- Kernel 2: 64 i-rows per wave, fully-unrolled K-loop.
// grid = (24 row-groups of 256, JS, 4 heads); block = (64,4).
// Mask stored transposed in LDS so the 4 row-tile words per iter = 1 ds_read_b128.
__global__ __launch_bounds__(256, 3) void gat_main_kernel(
    const unsigned* __restrict__ mask32, const short* __restrict__ htF,
    const float* __restrict__ srcv, const unsigned* __restrict__ tE1pk,
    const unsigned* __restrict__ tE2pk,
    float* __restrict__ pnum, float* __restrict__ pden)
{
    __shared__ unsigned smask[4 * 16 * SMT_STRIDE];   // 25.6 KB
    __shared__ uint4_t sE1v[96], sE2v[96];            // 3 KB

    const int lane = threadIdx.x;
    const int wy = threadIdx.y;
    const int jc = blockIdx.y;
    const int head = blockIdx.z;
    const int rb0 = blockIdx.x * 256;
    const int m = lane & 15, quad = lane >> 4;
    const int jbase = jc * JLEN;
    const int tid = wy * 64 + lane;

    // stage packed mask TRANSPOSED: word (row r, w) -> smask[(wyr*16+mm)*100 + w*4 + tt]
    //   r = wyr*64 + tt*16 + mm
    #pragma unroll
    for (int it = 0; it < 6; ++it) {
        const int flat = it * 256 + tid;            // 0..1535
        const int r = flat / 6, w4 = flat % 6;
        const uint4_t v = *(const uint4_t*)(mask32 + (size_t)(rb0 + r) * NWORDS + jc * NW + w4 * 4);
        const int wyr = r >> 6, tt = (r >> 4) & 3, mm = r & 15;
        unsigned* base = &smask[(wyr * 16 + mm) * SMT_STRIDE + tt];
        base[(w4 * 4 + 0) * 4] = v.x;
        base[(w4 * 4 + 1) * 4] = v.y;
        base[(w4 * 4 + 2) * 4] = v.z;
        base[(w4 * 4 + 3) * 4] = v.w;
    }
    // stage E1/E2 slice (96 uint4 each)
    if (tid < 192) {
        const unsigned* g = (tid < 96)
            ? (tE1pk + head * (N_NODES/2) + (jbase >> 1) + tid * 4)
            : (tE2pk + head * (N_NODES/2) + (jbase >> 1) + (tid - 96) * 4);
        const uint4_t v = *(const uint4_t*)g;
        if (tid < 96) sE1v[tid] = v; else sE2v[tid - 96] = v;
    }
    __syncthreads();

    const int rowbase = rb0 + wy * 64;
    half2_t e1s[4], e2s[4];
    #pragma unroll
    for (int t = 0; t < 4; ++t) {
        const float sv = srcv[head * N_NODES + rowbase + t * 16 + m];
        const _Float16 a1 = (_Float16)__expf(sv);
        const _Float16 a2 = (_Float16)__expf(0.2f * sv);
        e1s[t] = (half2_t){a1, a1};
        e2s[t] = (half2_t){a2, a2};
    }

    const short* fb = htF + ((size_t)(head * 192 + (jbase >> 5)) * 4) * 512 + (m * 4 + quad) * 8;
    const unsigned* mrow = &smask[(wy * 16 + m) * SMT_STRIDE];

    half8_t bones;
    #pragma unroll
    for (int u = 0; u < 8; ++u) bones[u] = (_Float16)1.0f;

    floatx4 accN[4][4];
    floatx4 accD[4];
    #pragma unroll
    for (int t = 0; t < 4; ++t) {
        accD[t] = (floatx4){0,0,0,0};
        #pragma unroll
        for (int c = 0; c < 4; ++c) accN[t][c] = (floatx4){0,0,0,0};
    }

    #pragma unroll
    for (int w = 0; w < NW; ++w) {
        half8_t b[4];
        #pragma unroll
        for (int c = 0; c < 4; ++c)
            b[c] = *(const half8_t*)(fb + (size_t)w * 2048 + c * 512);

        const uint4_t mq = *(const uint4_t*)(mrow + w * 4);   // t=0..3 mask words
        const uint4_t E1 = sE1v[w * 4 + quad];
        const uint4_t E2 = sE2v[w * 4 + quad];
        const unsigned mqa[4] = {mq.x, mq.y, mq.z, mq.w};
        const unsigned E1a[4] = {E1.x, E1.y, E1.z, E1.w};
        const unsigned E2a[4] = {E2.x, E2.y, E2.z, E2.w};

        #pragma unroll
        for (int t = 0; t < 4; ++t) {
            const unsigned bits = (mqa[t] >> (quad * 8)) & 0xffu;
            const short2v tt = __builtin_bit_cast(short2v, bits * 0x10001u);
            uint4_t af_u;
            #pragma unroll
            for (int p = 0; p < 4; ++p) {
                const short2v shl = (p == 0) ? (short2v){15,14} : (p == 1) ? (short2v){13,12}
                                 : (p == 2) ? (short2v){11,10} : (short2v){9,8};
                const short2v k = (tt << shl) >> (short2v){15,15};   // 0xFFFF/0x0000 per half
                const half2_t p1 = __builtin_bit_cast(half2_t, E1a[p]) * e1s[t];
                const half2_t p2 = __builtin_bit_cast(half2_t, E2a[p]) * e2s[t];
                const half2_t mx = __builtin_elementwise_max(p1, p2); // exp(lrelu) = max of exps
                const unsigned r = __builtin_bit_cast(unsigned, mx) & __builtin_bit_cast(unsigned, k);
                if (p == 0) af_u.x = r; else if (p == 1) af_u.y = r;
                else if (p == 2) af_u.z = r; else af_u.w = r;
            }
            const half8_t af = __builtin_bit_cast(half8_t, af_u);
            #pragma unroll
            for (int c = 0; c < 4; ++c)
                accN[t][c] = __builtin_amdgcn_mfma_f32_16x16x32_f16(af, b[c], accN[t][c], 0, 0, 0);
            accD[t] = __builtin_amdgcn_mfma_f32_16x16x32_f16(af, bones, accD[t], 0, 0, 0);
        }
    }

    const int slot = jc * N_HEADS + head;
    #pragma unroll
    for (int t = 0; t < 4; ++t) {
        if (m == 0) {
            #pragma unroll
            for (int r = 0; r < 4; ++r)
                pden[slot * N_NODES + rowbase + t * 16 + quad * 4 + r] = accD[t][r];
        }
        #pragma unroll
        for (int r = 0; r < 4; ++r) {
            const int gi = rowbase + t * 16 + quad * 4 + r;
            float* np_ = pnum + ((size_t)slot * N_NODES + gi) * N_HID + m;
            np_[0]  = accN[t][0][r];
            np_[16] = accN[t][1][r];
            np_[32] = accN[t][2][r];
            np_[48] = accN[t][3][r];
        }
    }
}

// ---------------- Kernel 3: reduce j-chunks, divide, mean over heads (float4)
__global__ __launch_bounds__(256) void finalize_kernel(
    const float* __restrict__ pnum, const float* __restrict__ pden,
    float* __restrict__ out)
{
    const int idx = blockIdx.x * 256 + threadIdx.x;   // over N_NODES*16
    if (idx >= N_NODES * 16) return;
    const int i = idx >> 4;
    const int d4 = (idx & 15) * 4;
    float sx = 0.f, sy = 0.f, sz = 0.f, sw = 0.f;
    #pragma unroll
    for (int hh = 0; hh < N_HEADS; ++hh) {
        float nx = 0.f, ny = 0.f, nz = 0.f, nw_ = 0.f, ds = 0.f;
        #pragma unroll
        for (int jc = 0; jc < JS; ++jc) {
            const int slot = jc * N_HEADS + hh;
            const float4 v = *(const float4*)(pnum + ((size_t)slot * N_NODES + i) * N_HID + d4);
            nx += v.x; ny += v.y; nz += v.z; nw_ += v.w;
            ds += pden[slot * N_NODES + i];
        }
        const float r = 1.0f / ds;
        sx += nx * r; sy += ny * r; sz += nz * r; sw += nw_ * r;
    }
    float4 o; o.x = 0.25f * sx; o.y = 0.25f * sy; o.z = 0.25f * sz; o.w = 0.25f * sw;
    *(float4*)(out + (size_t)i * N_HID + d4) = o;
}

extern "C" void kernel_launch(void* const* d_in, const int* in_sizes, int n_in,
                              void* d_out, int out_size, void* d_ws, size_t ws_size,
                              hipStream_t stream)
{
    const float* h   = (const float*)d_in[0];
    const int*   adj = (const int*)d_in[1];
    const float* W   = (const float*)d_in[2];
    const float* a   = (const float*)d_in[3];
    float* out = (float*)d_out;

    char* ws = (char*)d_ws;
    short* htF = (short*)ws;
    size_t off = (size_t)N_HEADS * N_HID * N_NODES * 2;              // 3.1 MB
    float* srcv = (float*)(ws + off);        off += (size_t)N_HEADS * N_NODES * 4;
    unsigned* tE1pk = (unsigned*)(ws + off); off += (size_t)N_HEADS * (N_NODES/2) * 4;
    unsigned* tE2pk = (unsigned*)(ws + off); off += (size_t)N_HEADS * (N_NODES/2) * 4;
    unsigned* mask32 = (unsigned*)(ws + off); off += (size_t)N_NODES * NWORDS * 4;   // 4.7 MB
    float* pnum = (float*)(ws + off);        off += (size_t)JS * N_HEADS * N_NODES * N_HID * 4;  // 50.3 MB
    float* pden = (float*)(ws + off);

    pack_adj_kernel<<<1536, 256, 0, stream>>>(adj, mask32);
    ht_gemm_kernel<<<dim3(N_NODES / 32, N_HEADS), 256, 0, stream>>>(h, W, a, htF, srcv, tE1pk, tE2pk);
    gat_main_kernel<<<dim3(N_NODES / 256, JS, N_HEADS), dim3(64, 4), 0, stream>>>(
        mask32, htF, srcv, tE1pk, tE2pk, pnum, pden);
    finalize_kernel<<<dim3((N_NODES * 16 + 255) / 256), 256, 0, stream>>>(pnum, pden, out);
}

// Round 11
// 277.401 us; speedup vs baseline: 1.1285x; 1.1285x over previous
//
#include <hip/hip_runtime.h>
#include <hip/hip_bf16.h>

#define N_NODES 6144
#define IN_F 256
#define N_HEADS 4
#define N_HID 64
#define JS 8
#define JLEN (N_NODES / JS)        // 768
#define NW (JLEN / 32)             // 24 mask words per chunk row
#define SM_STRIDE 28               // words/row; 2-way bank alias only (free)

typedef __attribute__((ext_vector_type(4))) float floatx4;
typedef _Float16 half2_t __attribute__((ext_vector_type(2)));
typedef _Float16 half8_t __attribute__((ext_vector_type(8)));
typedef __attribute__((ext_vector_type(4))) unsigned uint4_t;
typedef short short2v __attribute__((ext_vector_type(2)));

// ---------------- Kernel 1: ht = h @ W (fp32); epilogue -> htF (f16 MFMA B-fragment layout),
//   srcv (f32), tE1pk/tE2pk = f16x2 pairs of exp(tgt), exp(0.2*tgt).
__global__ __launch_bounds__(256) void ht_gemm_kernel(
    const float* __restrict__ h, const float* __restrict__ W,
    const float* __restrict__ a, short* __restrict__ htF,
    float* __restrict__ srcv, unsigned* __restrict__ tE1pk, unsigned* __restrict__ tE2pk)
{
    __shared__ float As[32][34];
    __shared__ float Bs[32][68];
    __shared__ float redS[32][16];
    __shared__ float redT[32][16];
    __shared__ unsigned short eh1[32], eh2[32];

    const int head = blockIdx.y;
    const int i0 = blockIdx.x * 32;
    const int tid = threadIdx.x;
    const int tx = tid & 15, ty = tid >> 4;

    float acc[2][4] = {};

    for (int k0 = 0; k0 < IN_F; k0 += 32) {
        __syncthreads();
        {
            const int m = tid >> 3, kq = tid & 7;
            const float4 v = *(const float4*)(h + (i0 + m) * IN_F + k0 + kq * 4);
            As[kq*4+0][m] = v.x; As[kq*4+1][m] = v.y;
            As[kq*4+2][m] = v.z; As[kq*4+3][m] = v.w;
        }
        #pragma unroll
        for (int it = 0; it < 2; ++it) {
            int l = it * 256 + tid;
            int k = l >> 4, nq = l & 15;
            *(float4*)&Bs[k][nq*4] = *(const float4*)(W + (k0 + k) * 256 + head * 64 + nq * 4);
        }
        __syncthreads();
        #pragma unroll
        for (int kk = 0; kk < 32; ++kk) {
            const float2 av = *(const float2*)&As[kk][ty*2];
            const float4 bv = *(const float4*)&Bs[kk][tx*4];
            const float aa[2] = {av.x, av.y};
            const float bb[4] = {bv.x, bv.y, bv.z, bv.w};
            #pragma unroll
            for (int r = 0; r < 2; ++r)
                #pragma unroll
                for (int c = 0; c < 4; ++c)
                    acc[r][c] = fmaf(aa[r], bb[c], acc[r][c]);
        }
    }

    #pragma unroll
    for (int r = 0; r < 2; ++r)
        #pragma unroll
        for (int c2 = 0; c2 < 4; ++c2) {
            const int d = tx * 4 + c2;
            const int j = i0 + ty * 2 + r;
            const int jt = j >> 5, q = (j >> 3) & 3, u = j & 7;
            const int c = d >> 4, n = d & 15;
            const size_t F = (((((size_t)head * 192 + jt) * 4 + c) * 16 + n) * 4 + q) * 8 + u;
            const _Float16 hv = (_Float16)acc[r][c2];
            htF[F] = *(const short*)&hv;
        }

    float as_[4], at_[4];
    #pragma unroll
    for (int c = 0; c < 4; ++c) {
        as_[c] = a[head * 128 + tx * 4 + c];
        at_[c] = a[head * 128 + 64 + tx * 4 + c];
    }
    #pragma unroll
    for (int r = 0; r < 2; ++r) {
        float ps = 0.f, pt = 0.f;
        #pragma unroll
        for (int c = 0; c < 4; ++c) {
            ps = fmaf(acc[r][c], as_[c], ps);
            pt = fmaf(acc[r][c], at_[c], pt);
        }
        redS[ty*2+r][tx] = ps;
        redT[ty*2+r][tx] = pt;
    }
    __syncthreads();
    if (tid < 64) {
        const int row = tid & 31;
        const float* src = (tid < 32) ? &redS[row][0] : &redT[row][0];
        float s = 0.f;
        #pragma unroll
        for (int x = 0; x < 16; ++x) s += src[x];
        if (tid < 32) {
            srcv[head * N_NODES + i0 + row] = s;
        } else {
            const _Float16 E1 = (_Float16)__expf(s);
            const _Float16 E2 = (_Float16)__expf(0.2f * s);
            eh1[row] = *(const unsigned short*)&E1;
            eh2[row] = *(const unsigned short*)&E2;
        }
    }
    __syncthreads();
    if (tid < 16) {
        const unsigned v1 = (unsigned)eh1[2*tid] | ((unsigned)eh1[2*tid+1] << 16);
        const unsigned v2 = (unsigned)eh2[2*tid] | ((unsigned)eh2[2*tid+1] << 16);
        tE1pk[head * (N_NODES/2) + i0/2 + tid] = v1;
        tE2pk[head * (N_NODES/2) + i0/2 + tid] = v2;
    }
}

// ---------------- Kernel 2: fused adj-pack + masked rank-1 softmax + PV.
// grid = (96 i-tiles of 64 rows, JS); block = (64,4): wave y = head y.
// Block stages its 64x768 adj slice ONCE as bits in LDS (7.2 KB), shared by all 4 heads.
// 64 rows per wave (4 MFMA row-tiles), rolled loop, depth-1 prefetch (R8 structure).
__global__ __launch_bounds__(256, 3) void gat_main_kernel(
    const int* __restrict__ adj, const short* __restrict__ htF,
    const float* __restrict__ srcv, const unsigned* __restrict__ tE1pk,
    const unsigned* __restrict__ tE2pk,
    float* __restrict__ pnum, float* __restrict__ pden)
{
    __shared__ unsigned smask[64 * SM_STRIDE];   // 7.2 KB

    const int lane = threadIdx.x;
    const int head = threadIdx.y;                // wave = head
    const int jc = blockIdx.y;
    const int rb0 = blockIdx.x * 64;
    const int m = lane & 15, quad = lane >> 4;
    const int jbase = jc * JLEN;
    const int tid = head * 64 + lane;

    // stage + pack adjacency: 64 rows x 24 words; thread packs 6 words (8 int4 each)
    for (int wi = 0; wi < 6; ++wi) {
        const int flat = wi * 256 + tid;         // 0..1535
        const int r = flat / NW, w = flat % NW;
        const int* p = adj + (size_t)(rb0 + r) * N_NODES + jbase + w * 32;
        unsigned mw = 0;
        #pragma unroll
        for (int k = 0; k < 8; ++k) {
            const int4 v = *(const int4*)(p + k * 4);     // adj values are {0,1}
            mw |= (unsigned)v.x << (k * 4 + 0);
            mw |= (unsigned)v.y << (k * 4 + 1);
            mw |= (unsigned)v.z << (k * 4 + 2);
            mw |= (unsigned)v.w << (k * 4 + 3);
        }
        smask[r * SM_STRIDE + w] = mw;
    }
    __syncthreads();

    half2_t e1s[4], e2s[4];
    #pragma unroll
    for (int t = 0; t < 4; ++t) {
        const float sv = srcv[head * N_NODES + rb0 + t * 16 + m];
        const _Float16 a1 = (_Float16)__expf(sv);
        const _Float16 a2 = (_Float16)__expf(0.2f * sv);
        e1s[t] = (half2_t){a1, a1};
        e2s[t] = (half2_t){a2, a2};
    }

    const unsigned* pe1 = tE1pk + head * (N_NODES/2) + (jbase >> 1);
    const unsigned* pe2 = tE2pk + head * (N_NODES/2) + (jbase >> 1);
    const short* fb = htF + ((size_t)(head * 192 + (jbase >> 5)) * 4) * 512 + (m * 4 + quad) * 8;
    const unsigned* mrow = &smask[m * SM_STRIDE];   // tile t adds t*16*SM_STRIDE

    half8_t bones;
    #pragma unroll
    for (int u = 0; u < 8; ++u) bones[u] = (_Float16)1.0f;

    floatx4 accN[4][4];
    floatx4 accD[4];
    #pragma unroll
    for (int t = 0; t < 4; ++t) {
        accD[t] = (floatx4){0,0,0,0};
        #pragma unroll
        for (int c = 0; c < 4; ++c) accN[t][c] = (floatx4){0,0,0,0};
    }

    // depth-1 prefetch: b-fragments + E for w=0
    half8_t bn[4];
    #pragma unroll
    for (int c = 0; c < 4; ++c) bn[c] = *(const half8_t*)(fb + c * 512);
    uint4_t E1n = *(const uint4_t*)(pe1 + quad * 4);
    uint4_t E2n = *(const uint4_t*)(pe2 + quad * 4);

    for (int w = 0; w < NW; ++w) {
        half8_t bc[4];
        #pragma unroll
        for (int c = 0; c < 4; ++c) bc[c] = bn[c];
        const uint4_t E1 = E1n, E2 = E2n;

        const int wn = (w + 1 < NW) ? (w + 1) : w;      // clamped prefetch
        #pragma unroll
        for (int c = 0; c < 4; ++c)
            bn[c] = *(const half8_t*)(fb + (size_t)wn * 2048 + c * 512);
        E1n = *(const uint4_t*)(pe1 + wn * 16 + quad * 4);
        E2n = *(const uint4_t*)(pe2 + wn * 16 + quad * 4);

        const unsigned E1a[4] = {E1.x, E1.y, E1.z, E1.w};
        const unsigned E2a[4] = {E2.x, E2.y, E2.z, E2.w};

        #pragma unroll
        for (int t = 0; t < 4; ++t) {
            const unsigned bits = (mrow[t * (16*SM_STRIDE) + w] >> (quad * 8)) & 0xffu;
            const short2v tt = __builtin_bit_cast(short2v, bits * 0x10001u);
            uint4_t af_u;
            #pragma unroll
            for (int p = 0; p < 4; ++p) {
                const short2v shl = (p == 0) ? (short2v){15,14} : (p == 1) ? (short2v){13,12}
                                 : (p == 2) ? (short2v){11,10} : (short2v){9,8};
                const short2v k = (tt << shl) >> (short2v){15,15};   // 0xFFFF/0x0000 per half
                const half2_t p1 = __builtin_bit_cast(half2_t, E1a[p]) * e1s[t];
                const half2_t p2 = __builtin_bit_cast(half2_t, E2a[p]) * e2s[t];
                const half2_t mx = __builtin_elementwise_max(p1, p2); // exp(lrelu) = max of exps
                const unsigned r = __builtin_bit_cast(unsigned, mx) & __builtin_bit_cast(unsigned, k);
                if (p == 0) af_u.x = r; else if (p == 1) af_u.y = r;
                else if (p == 2) af_u.z = r; else af_u.w = r;
            }
            const half8_t af = __builtin_bit_cast(half8_t, af_u);
            #pragma unroll
            for (int c = 0; c < 4; ++c)
                accN[t][c] = __builtin_amdgcn_mfma_f32_16x16x32_f16(af, bc[c], accN[t][c], 0, 0, 0);
            accD[t] = __builtin_amdgcn_mfma_f32_16x16x32_f16(af, bones, accD[t], 0, 0, 0);
        }
    }

    const int slot = jc * N_HEADS + head;
    #pragma unroll
    for (int t = 0; t < 4; ++t) {
        if (m == 0) {
            #pragma unroll
            for (int r = 0; r < 4; ++r)
                pden[slot * N_NODES + rb0 + t * 16 + quad * 4 + r] = accD[t][r];
        }
        #pragma unroll
        for (int r = 0; r < 4; ++r) {
            const int gi = rb0 + t * 16 + quad * 4 + r;
            float* np_ = pnum + ((size_t)slot * N_NODES + gi) * N_HID + m;
            np_[0]  = accN[t][0][r];
            np_[16] = accN[t][1][r];
            np_[32] = accN[t][2][r];
            np_[48] = accN[t][3][r];
        }
    }
}

// ---------------- Kernel 3: reduce j-chunks, divide, mean over heads (float4)
__global__ __launch_bounds__(256) void finalize_kernel(
    const float* __restrict__ pnum, const float* __restrict__ pden,
    float* __restrict__ out)
{
    const int idx = blockIdx.x * 256 + threadIdx.x;   // over N_NODES*16
    if (idx >= N_NODES * 16) return;
    const int i = idx >> 4;
    const int d4 = (idx & 15) * 4;
    float sx = 0.f, sy = 0.f, sz = 0.f, sw = 0.f;
    #pragma unroll
    for (int hh = 0; hh < N_HEADS; ++hh) {
        float nx = 0.f, ny = 0.f, nz = 0.f, nw_ = 0.f, ds = 0.f;
        #pragma unroll
        for (int jc = 0; jc < JS; ++jc) {
            const int slot = jc * N_HEADS + hh;
            const float4 v = *(const float4*)(pnum + ((size_t)slot * N_NODES + i) * N_HID + d4);
            nx += v.x; ny += v.y; nz += v.z; nw_ += v.w;
            ds += pden[slot * N_NODES + i];
        }
        const float r = 1.0f / ds;
        sx += nx * r; sy += ny * r; sz += nz * r; sw += nw_ * r;
    }
    float4 o; o.x = 0.25f * sx; o.y = 0.25f * sy; o.z = 0.25f * sz; o.w = 0.25f * sw;
    *(float4*)(out + (size_t)i * N_HID + d4) = o;
}

extern "C" void kernel_launch(void* const* d_in, const int* in_sizes, int n_in,
                              void* d_out, int out_size, void* d_ws, size_t ws_size,
                              hipStream_t stream)
{
    const float* h   = (const float*)d_in[0];
    const int*   adj = (const int*)d_in[1];
    const float* W   = (const float*)d_in[2];
    const float* a   = (const float*)d_in[3];
    float* out = (float*)d_out;

    char* ws = (char*)d_ws;
    short* htF = (short*)ws;
    size_t off = (size_t)N_HEADS * N_HID * N_NODES * 2;              // 3.1 MB
    float* srcv = (float*)(ws + off);        off += (size_t)N_HEADS * N_NODES * 4;
    unsigned* tE1pk = (unsigned*)(ws + off); off += (size_t)N_HEADS * (N_NODES/2) * 4;
    unsigned* tE2pk = (unsigned*)(ws + off); off += (size_t)N_HEADS * (N_NODES/2) * 4;
    float* pnum = (float*)(ws + off);        off += (size_t)JS * N_HEADS * N_NODES * N_HID * 4;  // 50.3 MB
    float* pden = (float*)(ws + off);

    ht_gemm_kernel<<<dim3(N_NODES / 32, N_HEADS), 256, 0, stream>>>(h, W, a, htF, srcv, tE1pk, tE2pk);
    gat_main_kernel<<<dim3(N_NODES / 64, JS), dim3(64, 4), 0, stream>>>(
        adj, htF, srcv, tE1pk, tE2pk, pnum, pden);
    finalize_kernel<<<dim3((N_NODES * 16 + 255) / 256), 256, 0, stream>>>(pnum, pden, out);
}

// Round 12
// 271.693 us; speedup vs baseline: 1.1522x; 1.0210x over previous
//
#include <hip/hip_runtime.h>
#include <hip/hip_bf16.h>

#define N_NODES 6144
#define IN_F 256
#define N_HEADS 4
#define N_HID 64
#define JS 8
#define JLEN (N_NODES / JS)        // 768
#define NW (JLEN / 32)             // 24 mask words per chunk row
#define SM_STRIDE 28               // words/row; 2-way bank alias only (free)

typedef __attribute__((ext_vector_type(4))) float floatx4;
typedef _Float16 half2_t __attribute__((ext_vector_type(2)));
typedef _Float16 half8_t __attribute__((ext_vector_type(8)));
typedef __attribute__((ext_vector_type(4))) unsigned uint4_t;
typedef short short2v __attribute__((ext_vector_type(2)));

// ---------------- Kernel 1: ht = h @ W (fp32); epilogue -> htF (f16 MFMA B-fragment layout),
//   srcv (f32), tE1pk/tE2pk = f16x2 pairs of exp(tgt), exp(0.2*tgt).
__global__ __launch_bounds__(256) void ht_gemm_kernel(
    const float* __restrict__ h, const float* __restrict__ W,
    const float* __restrict__ a, short* __restrict__ htF,
    float* __restrict__ srcv, unsigned* __restrict__ tE1pk, unsigned* __restrict__ tE2pk)
{
    __shared__ float As[32][34];
    __shared__ float Bs[32][68];
    __shared__ float redS[32][16];
    __shared__ float redT[32][16];
    __shared__ unsigned short eh1[32], eh2[32];

    const int head = blockIdx.y;
    const int i0 = blockIdx.x * 32;
    const int tid = threadIdx.x;
    const int tx = tid & 15, ty = tid >> 4;

    float acc[2][4] = {};

    for (int k0 = 0; k0 < IN_F; k0 += 32) {
        __syncthreads();
        {
            const int m = tid >> 3, kq = tid & 7;
            const float4 v = *(const float4*)(h + (i0 + m) * IN_F + k0 + kq * 4);
            As[kq*4+0][m] = v.x; As[kq*4+1][m] = v.y;
            As[kq*4+2][m] = v.z; As[kq*4+3][m] = v.w;
        }
        #pragma unroll
        for (int it = 0; it < 2; ++it) {
            int l = it * 256 + tid;
            int k = l >> 4, nq = l & 15;
            *(float4*)&Bs[k][nq*4] = *(const float4*)(W + (k0 + k) * 256 + head * 64 + nq * 4);
        }
        __syncthreads();
        #pragma unroll
        for (int kk = 0; kk < 32; ++kk) {
            const float2 av = *(const float2*)&As[kk][ty*2];
            const float4 bv = *(const float4*)&Bs[kk][tx*4];
            const float aa[2] = {av.x, av.y};
            const float bb[4] = {bv.x, bv.y, bv.z, bv.w};
            #pragma unroll
            for (int r = 0; r < 2; ++r)
                #pragma unroll
                for (int c = 0; c < 4; ++c)
                    acc[r][c] = fmaf(aa[r], bb[c], acc[r][c]);
        }
    }

    #pragma unroll
    for (int r = 0; r < 2; ++r)
        #pragma unroll
        for (int c2 = 0; c2 < 4; ++c2) {
            const int d = tx * 4 + c2;
            const int j = i0 + ty * 2 + r;
            const int jt = j >> 5, q = (j >> 3) & 3, u = j & 7;
            const int c = d >> 4, n = d & 15;
            const size_t F = (((((size_t)head * 192 + jt) * 4 + c) * 16 + n) * 4 + q) * 8 + u;
            const _Float16 hv = (_Float16)acc[r][c2];
            htF[F] = *(const short*)&hv;
        }

    float as_[4], at_[4];
    #pragma unroll
    for (int c = 0; c < 4; ++c) {
        as_[c] = a[head * 128 + tx * 4 + c];
        at_[c] = a[head * 128 + 64 + tx * 4 + c];
    }
    #pragma unroll
    for (int r = 0; r < 2; ++r) {
        float ps = 0.f, pt = 0.f;
        #pragma unroll
        for (int c = 0; c < 4; ++c) {
            ps = fmaf(acc[r][c], as_[c], ps);
            pt = fmaf(acc[r][c], at_[c], pt);
        }
        redS[ty*2+r][tx] = ps;
        redT[ty*2+r][tx] = pt;
    }
    __syncthreads();
    if (tid < 64) {
        const int row = tid & 31;
        const float* src = (tid < 32) ? &redS[row][0] : &redT[row][0];
        float s = 0.f;
        #pragma unroll
        for (int x = 0; x < 16; ++x) s += src[x];
        if (tid < 32) {
            srcv[head * N_NODES + i0 + row] = s;
        } else {
            const _Float16 E1 = (_Float16)__expf(s);
            const _Float16 E2 = (_Float16)__expf(0.2f * s);
            eh1[row] = *(const unsigned short*)&E1;
            eh2[row] = *(const unsigned short*)&E2;
        }
    }
    __syncthreads();
    if (tid < 16) {
        const unsigned v1 = (unsigned)eh1[2*tid] | ((unsigned)eh1[2*tid+1] << 16);
        const unsigned v2 = (unsigned)eh2[2*tid] | ((unsigned)eh2[2*tid+1] << 16);
        tE1pk[head * (N_NODES/2) + i0/2 + tid] = v1;
        tE2pk[head * (N_NODES/2) + i0/2 + tid] = v2;
    }
}

// ---------------- Kernel 2: fused adj-pack + masked rank-1 softmax + PV.
// 1D grid of 768, XCD-aware swizzle: xcd = bid&7, idx = bid>>3, jc = idx/12,
// rb = (idx%12)*8 + xcd  -> blocks co-resident on one XCD share jc (htF slice L2-hot).
// block = (64,4): wave y = head y; 64 rows/wave, rolled loop, depth-1 b-frag prefetch.
__global__ __launch_bounds__(256, 3) void gat_main_kernel(
    const int* __restrict__ adj, const short* __restrict__ htF,
    const float* __restrict__ srcv, const unsigned* __restrict__ tE1pk,
    const unsigned* __restrict__ tE2pk,
    float* __restrict__ pnum, float* __restrict__ pden)
{
    __shared__ unsigned smask[64 * SM_STRIDE];   // 7.2 KB
    __shared__ unsigned sE1[4 * 384], sE2[4 * 384];  // 12 KB: E for all 4 heads of this jc

    const int bid = blockIdx.x;
    const int xcd = bid & 7;
    const int idx = bid >> 3;
    const int jc = idx / 12;
    const int rb0 = ((idx % 12) * 8 + xcd) * 64;

    const int lane = threadIdx.x;
    const int head = threadIdx.y;                // wave = head
    const int m = lane & 15, quad = lane >> 4;
    const int jbase = jc * JLEN;
    const int tid = head * 64 + lane;

    // stage + pack adjacency: 64 rows x 24 words; thread packs 6 words (8 int4 each)
    for (int wi = 0; wi < 6; ++wi) {
        const int flat = wi * 256 + tid;         // 0..1535
        const int r = flat / NW, w = flat % NW;
        const int* p = adj + (size_t)(rb0 + r) * N_NODES + jbase + w * 32;
        unsigned mw = 0;
        #pragma unroll
        for (int k = 0; k < 8; ++k) {
            const int4 v = *(const int4*)(p + k * 4);     // adj values are {0,1}
            mw |= (unsigned)v.x << (k * 4 + 0);
            mw |= (unsigned)v.y << (k * 4 + 1);
            mw |= (unsigned)v.z << (k * 4 + 2);
            mw |= (unsigned)v.w << (k * 4 + 3);
        }
        smask[r * SM_STRIDE + w] = mw;
    }
    // stage E1/E2 for all 4 heads of this jc: 768 uint4, 3 per thread
    #pragma unroll
    for (int it = 0; it < 3; ++it) {
        const int flat = it * 256 + tid;         // 0..767
        const int isE2 = flat >= 384;
        const int f = isE2 ? flat - 384 : flat;  // 0..383
        const int hh = f / 96, w4 = f % 96;
        const unsigned* g = (isE2 ? tE2pk : tE1pk) + hh * (N_NODES/2) + (jbase >> 1) + w4 * 4;
        const uint4_t v = *(const uint4_t*)g;
        unsigned* dst = (isE2 ? sE2 : sE1) + hh * 384 + w4 * 4;
        dst[0] = v.x; dst[1] = v.y; dst[2] = v.z; dst[3] = v.w;
    }
    __syncthreads();

    half2_t e1s[4], e2s[4];
    #pragma unroll
    for (int t = 0; t < 4; ++t) {
        const float sv = srcv[head * N_NODES + rb0 + t * 16 + m];
        const _Float16 a1 = (_Float16)__expf(sv);
        const _Float16 a2 = (_Float16)__expf(0.2f * sv);
        e1s[t] = (half2_t){a1, a1};
        e2s[t] = (half2_t){a2, a2};
    }

    const short* fb = htF + ((size_t)(head * 192 + (jbase >> 5)) * 4) * 512 + (m * 4 + quad) * 8;
    const unsigned* mrow = &smask[m * SM_STRIDE];   // tile t adds t*16*SM_STRIDE
    const unsigned* pe1 = &sE1[head * 384];
    const unsigned* pe2 = &sE2[head * 384];

    half8_t bones;
    #pragma unroll
    for (int u = 0; u < 8; ++u) bones[u] = (_Float16)1.0f;

    floatx4 accN[4][4];
    floatx4 accD[4];
    #pragma unroll
    for (int t = 0; t < 4; ++t) {
        accD[t] = (floatx4){0,0,0,0};
        #pragma unroll
        for (int c = 0; c < 4; ++c) accN[t][c] = (floatx4){0,0,0,0};
    }

    // depth-1 prefetch of b-fragments
    half8_t bn[4];
    #pragma unroll
    for (int c = 0; c < 4; ++c) bn[c] = *(const half8_t*)(fb + c * 512);

    for (int w = 0; w < NW; ++w) {
        half8_t bc[4];
        #pragma unroll
        for (int c = 0; c < 4; ++c) bc[c] = bn[c];
        const int wn = (w + 1 < NW) ? (w + 1) : w;      // clamped prefetch
        #pragma unroll
        for (int c = 0; c < 4; ++c)
            bn[c] = *(const half8_t*)(fb + (size_t)wn * 2048 + c * 512);

        const uint4_t E1 = *(const uint4_t*)(pe1 + w * 16 + quad * 4);   // ds_read_b128
        const uint4_t E2 = *(const uint4_t*)(pe2 + w * 16 + quad * 4);
        const unsigned E1a[4] = {E1.x, E1.y, E1.z, E1.w};
        const unsigned E2a[4] = {E2.x, E2.y, E2.z, E2.w};

        #pragma unroll
        for (int t = 0; t < 4; ++t) {
            const unsigned bits = (mrow[t * (16*SM_STRIDE) + w] >> (quad * 8)) & 0xffu;
            const short2v tt = __builtin_bit_cast(short2v, bits * 0x10001u);
            uint4_t af_u;
            #pragma unroll
            for (int p = 0; p < 4; ++p) {
                const short2v shl = (p == 0) ? (short2v){15,14} : (p == 1) ? (short2v){13,12}
                                 : (p == 2) ? (short2v){11,10} : (short2v){9,8};
                const short2v k = (tt << shl) >> (short2v){15,15};   // 0xFFFF/0x0000 per half
                const half2_t p1 = __builtin_bit_cast(half2_t, E1a[p]) * e1s[t];
                const half2_t p2 = __builtin_bit_cast(half2_t, E2a[p]) * e2s[t];
                const half2_t mx = __builtin_elementwise_max(p1, p2); // exp(lrelu) = max of exps
                const unsigned r = __builtin_bit_cast(unsigned, mx) & __builtin_bit_cast(unsigned, k);
                if (p == 0) af_u.x = r; else if (p == 1) af_u.y = r;
                else if (p == 2) af_u.z = r; else af_u.w = r;
            }
            const half8_t af = __builtin_bit_cast(half8_t, af_u);
            #pragma unroll
            for (int c = 0; c < 4; ++c)
                accN[t][c] = __builtin_amdgcn_mfma_f32_16x16x32_f16(af, bc[c], accN[t][c], 0, 0, 0);
            accD[t] = __builtin_amdgcn_mfma_f32_16x16x32_f16(af, bones, accD[t], 0, 0, 0);
        }
    }

    const int slot = jc * N_HEADS + head;
    #pragma unroll
    for (int t = 0; t < 4; ++t) {
        if (m == 0) {
            #pragma unroll
            for (int r = 0; r < 4; ++r)
                pden[slot * N_NODES + rb0 + t * 16 + quad * 4 + r] = accD[t][r];
        }
        #pragma unroll
        for (int r = 0; r < 4; ++r) {
            const int gi = rb0 + t * 16 + quad * 4 + r;
            float* np_ = pnum + ((size_t)slot * N_NODES + gi) * N_HID + m;
            np_[0]  = accN[t][0][r];
            np_[16] = accN[t][1][r];
            np_[32] = accN[t][2][r];
            np_[48] = accN[t][3][r];
        }
    }
}

// ---------------- Kernel 3: reduce j-chunks, divide, mean over heads (float4)
__global__ __launch_bounds__(256) void finalize_kernel(
    const float* __restrict__ pnum, const float* __restrict__ pden,
    float* __restrict__ out)
{
    const int idx = blockIdx.x * 256 + threadIdx.x;   // over N_NODES*16
    if (idx >= N_NODES * 16) return;
    const int i = idx >> 4;
    const int d4 = (idx & 15) * 4;
    float sx = 0.f, sy = 0.f, sz = 0.f, sw = 0.f;
    #pragma unroll
    for (int hh = 0; hh < N_HEADS; ++hh) {
        float nx = 0.f, ny = 0.f, nz = 0.f, nw_ = 0.f, ds = 0.f;
        #pragma unroll
        for (int jc = 0; jc < JS; ++jc) {
            const int slot = jc * N_HEADS + hh;
            const float4 v = *(const float4*)(pnum + ((size_t)slot * N_NODES + i) * N_HID + d4);
            nx += v.x; ny += v.y; nz += v.z; nw_ += v.w;
            ds += pden[slot * N_NODES + i];
        }
        const float r = 1.0f / ds;
        sx += nx * r; sy += ny * r; sz += nz * r; sw += nw_ * r;
    }
    float4 o; o.x = 0.25f * sx; o.y = 0.25f * sy; o.z = 0.25f * sz; o.w = 0.25f * sw;
    *(float4*)(out + (size_t)i * N_HID + d4) = o;
}

extern "C" void kernel_launch(void* const* d_in, const int* in_sizes, int n_in,
                              void* d_out, int out_size, void* d_ws, size_t ws_size,
                              hipStream_t stream)
{
    const float* h   = (const float*)d_in[0];
    const int*   adj = (const int*)d_in[1];
    const float* W   = (const float*)d_in[2];
    const float* a   = (const float*)d_in[3];
    float* out = (float*)d_out;

    char* ws = (char*)d_ws;
    short* htF = (short*)ws;
    size_t off = (size_t)N_HEADS * N_HID * N_NODES * 2;              // 3.1 MB
    float* srcv = (float*)(ws + off);        off += (size_t)N_HEADS * N_NODES * 4;
    unsigned* tE1pk = (unsigned*)(ws + off); off += (size_t)N_HEADS * (N_NODES/2) * 4;
    unsigned* tE2pk = (unsigned*)(ws + off); off += (size_t)N_HEADS * (N_NODES/2) * 4;
    float* pnum = (float*)(ws + off);        off += (size_t)JS * N_HEADS * N_NODES * N_HID * 4;  // 50.3 MB
    float* pden = (float*)(ws + off);

    ht_gemm_kernel<<<dim3(N_NODES / 32, N_HEADS), 256, 0, stream>>>(h, W, a, htF, srcv, tE1pk, tE2pk);
    gat_main_kernel<<<768, dim3(64, 4), 0, stream>>>(
        adj, htF, srcv, tE1pk, tE2pk, pnum, pden);
    finalize_kernel<<<dim3((N_NODES * 16 + 255) / 256), 256, 0, stream>>>(pnum, pden, out);
}

// Round 13
// 270.237 us; speedup vs baseline: 1.1584x; 1.0054x over previous
//
#include <hip/hip_runtime.h>
#include <hip/hip_bf16.h>

#define N_NODES 6144
#define IN_F 256
#define N_HEADS 4
#define N_HID 64
#define JS 8
#define JLEN (N_NODES / JS)        // 768
#define NW (JLEN / 32)             // 24 mask words per chunk row
#define SM_STRIDE 28               // words/row; 8B-aligned u64 slots; 2-way bank alias only

typedef __attribute__((ext_vector_type(4))) float floatx4;
typedef _Float16 half2_t __attribute__((ext_vector_type(2)));
typedef _Float16 half8_t __attribute__((ext_vector_type(8)));
typedef __attribute__((ext_vector_type(4))) unsigned uint4_t;
typedef short short2v __attribute__((ext_vector_type(2)));

// ---------------- Kernel 1: ht = h @ W (fp32); epilogue -> htF (f16 MFMA B-fragment layout),
//   srcv (f32), tE1pk/tE2pk = f16x2 pairs of exp(tgt), exp(0.2*tgt).
__global__ __launch_bounds__(256) void ht_gemm_kernel(
    const float* __restrict__ h, const float* __restrict__ W,
    const float* __restrict__ a, short* __restrict__ htF,
    float* __restrict__ srcv, unsigned* __restrict__ tE1pk, unsigned* __restrict__ tE2pk)
{
    __shared__ float As[32][34];
    __shared__ float Bs[32][68];
    __shared__ float redS[32][16];
    __shared__ float redT[32][16];
    __shared__ unsigned short eh1[32], eh2[32];

    const int head = blockIdx.y;
    const int i0 = blockIdx.x * 32;
    const int tid = threadIdx.x;
    const int tx = tid & 15, ty = tid >> 4;

    float acc[2][4] = {};

    for (int k0 = 0; k0 < IN_F; k0 += 32) {
        __syncthreads();
        {
            const int m = tid >> 3, kq = tid & 7;
            const float4 v = *(const float4*)(h + (i0 + m) * IN_F + k0 + kq * 4);
            As[kq*4+0][m] = v.x; As[kq*4+1][m] = v.y;
            As[kq*4+2][m] = v.z; As[kq*4+3][m] = v.w;
        }
        #pragma unroll
        for (int it = 0; it < 2; ++it) {
            int l = it * 256 + tid;
            int k = l >> 4, nq = l & 15;
            *(float4*)&Bs[k][nq*4] = *(const float4*)(W + (k0 + k) * 256 + head * 64 + nq * 4);
        }
        __syncthreads();
        #pragma unroll
        for (int kk = 0; kk < 32; ++kk) {
            const float2 av = *(const float2*)&As[kk][ty*2];
            const float4 bv = *(const float4*)&Bs[kk][tx*4];
            const float aa[2] = {av.x, av.y};
            const float bb[4] = {bv.x, bv.y, bv.z, bv.w};
            #pragma unroll
            for (int r = 0; r < 2; ++r)
                #pragma unroll
                for (int c = 0; c < 4; ++c)
                    acc[r][c] = fmaf(aa[r], bb[c], acc[r][c]);
        }
    }

    #pragma unroll
    for (int r = 0; r < 2; ++r)
        #pragma unroll
        for (int c2 = 0; c2 < 4; ++c2) {
            const int d = tx * 4 + c2;
            const int j = i0 + ty * 2 + r;
            const int jt = j >> 5, q = (j >> 3) & 3, u = j & 7;
            const int c = d >> 4, n = d & 15;
            const size_t F = (((((size_t)head * 192 + jt) * 4 + c) * 16 + n) * 4 + q) * 8 + u;
            const _Float16 hv = (_Float16)acc[r][c2];
            htF[F] = *(const short*)&hv;
        }

    float as_[4], at_[4];
    #pragma unroll
    for (int c = 0; c < 4; ++c) {
        as_[c] = a[head * 128 + tx * 4 + c];
        at_[c] = a[head * 128 + 64 + tx * 4 + c];
    }
    #pragma unroll
    for (int r = 0; r < 2; ++r) {
        float ps = 0.f, pt = 0.f;
        #pragma unroll
        for (int c = 0; c < 4; ++c) {
            ps = fmaf(acc[r][c], as_[c], ps);
            pt = fmaf(acc[r][c], at_[c], pt);
        }
        redS[ty*2+r][tx] = ps;
        redT[ty*2+r][tx] = pt;
    }
    __syncthreads();
    if (tid < 64) {
        const int row = tid & 31;
        const float* src = (tid < 32) ? &redS[row][0] : &redT[row][0];
        float s = 0.f;
        #pragma unroll
        for (int x = 0; x < 16; ++x) s += src[x];
        if (tid < 32) {
            srcv[head * N_NODES + i0 + row] = s;
        } else {
            const _Float16 E1 = (_Float16)__expf(s);
            const _Float16 E2 = (_Float16)__expf(0.2f * s);
            eh1[row] = *(const unsigned short*)&E1;
            eh2[row] = *(const unsigned short*)&E2;
        }
    }
    __syncthreads();
    if (tid < 16) {
        const unsigned v1 = (unsigned)eh1[2*tid] | ((unsigned)eh1[2*tid+1] << 16);
        const unsigned v2 = (unsigned)eh2[2*tid] | ((unsigned)eh2[2*tid+1] << 16);
        tE1pk[head * (N_NODES/2) + i0/2 + tid] = v1;
        tE2pk[head * (N_NODES/2) + i0/2 + tid] = v2;
    }
}

// ---------------- Kernel 2: fused adj-pack (dense ballot staging) + masked softmax + PV.
// 1D grid of 768, XCD swizzle. block = (64,4): wave y = head y; 64 rows/wave.
// Staging: lane l reads adj int at j=64W+l (256B dense per instr); __ballot gives the
// 64-bit mask word in exactly the compute loop's bit order (bit l <-> j offset l).
__global__ __launch_bounds__(256, 3) void gat_main_kernel(
    const int* __restrict__ adj, const short* __restrict__ htF,
    const float* __restrict__ srcv, const unsigned* __restrict__ tE1pk,
    const unsigned* __restrict__ tE2pk,
    float* __restrict__ pnum, float* __restrict__ pden)
{
    __shared__ unsigned smask[64 * SM_STRIDE];       // 7.2 KB
    __shared__ unsigned sE1[4 * 384], sE2[4 * 384];  // 12 KB: E for all 4 heads of this jc

    const int bid = blockIdx.x;
    const int xcd = bid & 7;
    const int idx = bid >> 3;
    const int jc = idx / 12;
    const int rb0 = ((idx % 12) * 8 + xcd) * 64;

    const int lane = threadIdx.x;
    const int head = threadIdx.y;                // wave = head
    const int m = lane & 15, quad = lane >> 4;
    const int jbase = jc * JLEN;
    const int tid = head * 64 + lane;

    // ---- dense staging + ballot pack: 768 (row, W64) items, 192 per wave, 8-way unrolled
    const int* adjb = adj + (size_t)rb0 * N_NODES + jbase + lane;
    for (int k0 = 0; k0 < 192; k0 += 8) {
        int v[8];
        #pragma unroll
        for (int s = 0; s < 8; ++s) {
            const int f = (k0 + s) * 4 + head;   // 0..767
            const int r = f / 12, W = f % 12;    // 12 groups of 64 j per row
            v[s] = adjb[(size_t)r * N_NODES + W * 64];
        }
        #pragma unroll
        for (int s = 0; s < 8; ++s) {
            const unsigned long long b = __ballot(v[s] > 0);
            const int f = (k0 + s) * 4 + head;
            const int r = f / 12, W = f % 12;
            if (lane == 0)
                *(unsigned long long*)&smask[r * SM_STRIDE + 2 * W] = b;
        }
    }
    // stage E1/E2 for all 4 heads of this jc: 768 uint4, 3 per thread
    #pragma unroll
    for (int it = 0; it < 3; ++it) {
        const int flat = it * 256 + tid;         // 0..767
        const int isE2 = flat >= 384;
        const int f = isE2 ? flat - 384 : flat;  // 0..383
        const int hh = f / 96, w4 = f % 96;
        const unsigned* g = (isE2 ? tE2pk : tE1pk) + hh * (N_NODES/2) + (jbase >> 1) + w4 * 4;
        const uint4_t v = *(const uint4_t*)g;
        unsigned* dst = (isE2 ? sE2 : sE1) + hh * 384 + w4 * 4;
        dst[0] = v.x; dst[1] = v.y; dst[2] = v.z; dst[3] = v.w;
    }
    __syncthreads();

    half2_t e1s[4], e2s[4];
    #pragma unroll
    for (int t = 0; t < 4; ++t) {
        const float sv = srcv[head * N_NODES + rb0 + t * 16 + m];
        const _Float16 a1 = (_Float16)__expf(sv);
        const _Float16 a2 = (_Float16)__expf(0.2f * sv);
        e1s[t] = (half2_t){a1, a1};
        e2s[t] = (half2_t){a2, a2};
    }

    const short* fb = htF + ((size_t)(head * 192 + (jbase >> 5)) * 4) * 512 + (m * 4 + quad) * 8;
    const unsigned* mrow = &smask[m * SM_STRIDE];   // tile t adds t*16*SM_STRIDE
    const unsigned* pe1 = &sE1[head * 384];
    const unsigned* pe2 = &sE2[head * 384];

    half8_t bones;
    #pragma unroll
    for (int u = 0; u < 8; ++u) bones[u] = (_Float16)1.0f;

    floatx4 accN[4][4];
    floatx4 accD[4];
    #pragma unroll
    for (int t = 0; t < 4; ++t) {
        accD[t] = (floatx4){0,0,0,0};
        #pragma unroll
        for (int c = 0; c < 4; ++c) accN[t][c] = (floatx4){0,0,0,0};
    }

    // depth-1 prefetch of b-fragments
    half8_t bn[4];
    #pragma unroll
    for (int c = 0; c < 4; ++c) bn[c] = *(const half8_t*)(fb + c * 512);

    for (int w = 0; w < NW; ++w) {
        half8_t bc[4];
        #pragma unroll
        for (int c = 0; c < 4; ++c) bc[c] = bn[c];
        const int wn = (w + 1 < NW) ? (w + 1) : w;      // clamped prefetch
        #pragma unroll
        for (int c = 0; c < 4; ++c)
            bn[c] = *(const half8_t*)(fb + (size_t)wn * 2048 + c * 512);

        const uint4_t E1 = *(const uint4_t*)(pe1 + w * 16 + quad * 4);   // ds_read_b128
        const uint4_t E2 = *(const uint4_t*)(pe2 + w * 16 + quad * 4);
        const unsigned E1a[4] = {E1.x, E1.y, E1.z, E1.w};
        const unsigned E2a[4] = {E2.x, E2.y, E2.z, E2.w};

        #pragma unroll
        for (int t = 0; t < 4; ++t) {
            const unsigned bits = (mrow[t * (16*SM_STRIDE) + w] >> (quad * 8)) & 0xffu;
            const short2v tt = __builtin_bit_cast(short2v, bits * 0x10001u);
            uint4_t af_u;
            #pragma unroll
            for (int p = 0; p < 4; ++p) {
                const short2v shl = (p == 0) ? (short2v){15,14} : (p == 1) ? (short2v){13,12}
                                 : (p == 2) ? (short2v){11,10} : (short2v){9,8};
                const short2v k = (tt << shl) >> (short2v){15,15};   // 0xFFFF/0x0000 per half
                const half2_t p1 = __builtin_bit_cast(half2_t, E1a[p]) * e1s[t];
                const half2_t p2 = __builtin_bit_cast(half2_t, E2a[p]) * e2s[t];
                const half2_t mx = __builtin_elementwise_max(p1, p2); // exp(lrelu) = max of exps
                const unsigned r = __builtin_bit_cast(unsigned, mx) & __builtin_bit_cast(unsigned, k);
                if (p == 0) af_u.x = r; else if (p == 1) af_u.y = r;
                else if (p == 2) af_u.z = r; else af_u.w = r;
            }
            const half8_t af = __builtin_bit_cast(half8_t, af_u);
            #pragma unroll
            for (int c = 0; c < 4; ++c)
                accN[t][c] = __builtin_amdgcn_mfma_f32_16x16x32_f16(af, bc[c], accN[t][c], 0, 0, 0);
            accD[t] = __builtin_amdgcn_mfma_f32_16x16x32_f16(af, bones, accD[t], 0, 0, 0);
        }
    }

    const int slot = jc * N_HEADS + head;
    #pragma unroll
    for (int t = 0; t < 4; ++t) {
        if (m == 0) {
            #pragma unroll
            for (int r = 0; r < 4; ++r)
                pden[slot * N_NODES + rb0 + t * 16 + quad * 4 + r] = accD[t][r];
        }
        #pragma unroll
        for (int r = 0; r < 4; ++r) {
            const int gi = rb0 + t * 16 + quad * 4 + r;
            float* np_ = pnum + ((size_t)slot * N_NODES + gi) * N_HID + m;
            np_[0]  = accN[t][0][r];
            np_[16] = accN[t][1][r];
            np_[32] = accN[t][2][r];
            np_[48] = accN[t][3][r];
        }
    }
}

// ---------------- Kernel 3: reduce j-chunks, divide, mean over heads (float4)
__global__ __launch_bounds__(256) void finalize_kernel(
    const float* __restrict__ pnum, const float* __restrict__ pden,
    float* __restrict__ out)
{
    const int idx = blockIdx.x * 256 + threadIdx.x;   // over N_NODES*16
    if (idx >= N_NODES * 16) return;
    const int i = idx >> 4;
    const int d4 = (idx & 15) * 4;
    float sx = 0.f, sy = 0.f, sz = 0.f, sw = 0.f;
    #pragma unroll
    for (int hh = 0; hh < N_HEADS; ++hh) {
        float nx = 0.f, ny = 0.f, nz = 0.f, nw_ = 0.f, ds = 0.f;
        #pragma unroll
        for (int jc = 0; jc < JS; ++jc) {
            const int slot = jc * N_HEADS + hh;
            const float4 v = *(const float4*)(pnum + ((size_t)slot * N_NODES + i) * N_HID + d4);
            nx += v.x; ny += v.y; nz += v.z; nw_ += v.w;
            ds += pden[slot * N_NODES + i];
        }
        const float r = 1.0f / ds;
        sx += nx * r; sy += ny * r; sz += nz * r; sw += nw_ * r;
    }
    float4 o; o.x = 0.25f * sx; o.y = 0.25f * sy; o.z = 0.25f * sz; o.w = 0.25f * sw;
    *(float4*)(out + (size_t)i * N_HID + d4) = o;
}

extern "C" void kernel_launch(void* const* d_in, const int* in_sizes, int n_in,
                              void* d_out, int out_size, void* d_ws, size_t ws_size,
                              hipStream_t stream)
{
    const float* h   = (const float*)d_in[0];
    const int*   adj = (const int*)d_in[1];
    const float* W   = (const float*)d_in[2];
    const float* a   = (const float*)d_in[3];
    float* out = (float*)d_out;

    char* ws = (char*)d_ws;
    short* htF = (short*)ws;
    size_t off = (size_t)N_HEADS * N_HID * N_NODES * 2;              // 3.1 MB
    float* srcv = (float*)(ws + off);        off += (size_t)N_HEADS * N_NODES * 4;
    unsigned* tE1pk = (unsigned*)(ws + off); off += (size_t)N_HEADS * (N_NODES/2) * 4;
    unsigned* tE2pk = (unsigned*)(ws + off); off += (size_t)N_HEADS * (N_NODES/2) * 4;
    float* pnum = (float*)(ws + off);        off += (size_t)JS * N_HEADS * N_NODES * N_HID * 4;  // 50.3 MB
    float* pden = (float*)(ws + off);

    ht_gemm_kernel<<<dim3(N_NODES / 32, N_HEADS), 256, 0, stream>>>(h, W, a, htF, srcv, tE1pk, tE2pk);
    gat_main_kernel<<<768, dim3(64, 4), 0, stream>>>(
        adj, htF, srcv, tE1pk, tE2pk, pnum, pden);
    finalize_kernel<<<dim3((N_NODES * 16 + 255) / 256), 256, 0, stream>>>(pnum, pden, out);
}